// Round 1
// baseline (36.604 us; speedup 1.0000x reference)
//
#include <hip/hip_runtime.h>
#include <cmath>

// Problem constants (fixed by setup_inputs)
#define KS     25
#define HALF   12
#define N_IN   16384
#define N_OUT  8192     // N_IN / STRIDE
#define C_DIM  128
#define B_DIM  16

#define OPT    8                    // outputs per thread
#define TPB    256
#define OUT_PER_BLOCK (OPT * TPB)   // 2048
#define SEGS   (N_OUT / OUT_PER_BLOCK)  // 4
#define NV     (2 * OPT + KS - 1 + 1)   // 40 input floats per thread

__global__ __launch_bounds__(TPB) void parabolic_pool_kernel(
    const float* __restrict__ f,
    const float* __restrict__ t,
    float* __restrict__ out) {

  const int blk = blockIdx.x;
  const int seg = blk & (SEGS - 1);
  const int row = blk >> 2;            // b*C + c
  const int c   = row & (C_DIM - 1);

  const float* __restrict__ frow = f + (size_t)row * N_IN;
  float* __restrict__ orow       = out + (size_t)row * N_OUT;

  // h[d] = -(d-12)^2 / (4*t[c])  computed as (d-12)^2 * (-0.25/t)
  const float tc   = t[c];
  const float minv = -0.25f / tc;
  float h[KS];
#pragma unroll
  for (int d = 0; d < KS; ++d) {
    const float z = (float)(d - HALF);
    h[d] = (z * z) * minv;
  }

  const int o_t   = seg * OUT_PER_BLOCK + (int)threadIdx.x * OPT;
  const int jbase = 2 * o_t - HALF;    // first input index needed (float4-aligned)

  float v[NV];
  if (jbase >= 0 && jbase + NV <= N_IN) {
    // fast path: 10 coalesced float4 loads
#pragma unroll
    for (int q = 0; q < NV / 4; ++q) {
      const float4 x = *reinterpret_cast<const float4*>(frow + jbase + 4 * q);
      v[4 * q + 0] = x.x;
      v[4 * q + 1] = x.y;
      v[4 * q + 2] = x.z;
      v[4 * q + 3] = x.w;
    }
  } else {
    // boundary path (2 threads per row): guarded scalar loads, -inf pad
#pragma unroll
    for (int k = 0; k < NV; ++k) {
      const int j = jbase + k;
      v[k] = (j >= 0 && j < N_IN) ? frow[j] : -INFINITY;
    }
  }

  float acc[OPT];
#pragma unroll
  for (int o = 0; o < OPT; ++o) {
    float m = v[2 * o] + h[0];
#pragma unroll
    for (int d = 1; d < KS; ++d) {
      m = fmaxf(m, v[2 * o + d] + h[d]);
    }
    acc[o] = m;
  }

  // two coalesced float4 stores (o_t is a multiple of 8)
  *reinterpret_cast<float4*>(orow + o_t) =
      make_float4(acc[0], acc[1], acc[2], acc[3]);
  *reinterpret_cast<float4*>(orow + o_t + 4) =
      make_float4(acc[4], acc[5], acc[6], acc[7]);
}

extern "C" void kernel_launch(void* const* d_in, const int* in_sizes, int n_in,
                              void* d_out, int out_size, void* d_ws, size_t ws_size,
                              hipStream_t stream) {
  const float* f = (const float*)d_in[0];   // (16, 128, 16384) f32
  const float* t = (const float*)d_in[1];   // (128,) f32
  float* out     = (float*)d_out;           // (16, 128, 8192) f32

  const int grid = B_DIM * C_DIM * SEGS;    // 8192 blocks
  parabolic_pool_kernel<<<grid, TPB, 0, stream>>>(f, t, out);
}